// Round 3
// baseline (587.571 us; speedup 1.0000x reference)
//
#include <hip/hip_runtime.h>
#include <hip/hip_bf16.h>

// DownBlock: pool(mean over 7 down-neighbors) -> conv1(K=7, 32->64) -> BN+LReLU
//         -> conv2(K=7, 64->64) -> BN+LReLU
// B=16, C_IN=32, C=64, V_FINE=163842, V=40962, K=7.
// Biases b1/b2 are dead: BN's mean subtraction absorbs per-channel constants.
// BN1+LReLU is fused into conv2's B-fragment load (conv2 is gather-latency
// bound; the extra VALU is free). BN2+LReLU is fused into final_out.

#define B_SZ     16
#define CIN      32
#define CMID     64
#define VFINE    163842
#define VC       40962
#define KNB      7

typedef __attribute__((ext_vector_type(8))) short  short8;   // 8 x bf16 (as i16)
typedef __attribute__((ext_vector_type(4))) float  f32x4;
typedef __attribute__((ext_vector_type(4))) unsigned short u16x4;

__device__ inline float bf2f(unsigned short u) {
    return __builtin_bit_cast(float, (unsigned int)(((unsigned int)u) << 16));
}
__device__ inline unsigned short f2bf(float f) {
    __hip_bfloat16 h = __float2bfloat16(f);
    return __builtin_bit_cast(unsigned short, h);
}

// ---------------------------------------------------------------------------
// Prep: reorder W into per-lane MFMA A-fragments, bf16. Also zeroes stats
// (replaces a hipMemsetAsync graph node).
// Fragment (chunk, otile): lane l, elem j ->  A[o = otile*16 + (l&15)][kk = (l>>4)*8 + j]
// conv1: chunk cc = k (7 chunks), c = kk.        W1[o][c*7+k]
// conv2: chunk cc = k*2 + ch (14), c = ch*32+kk. W2[o][c*7+k]
// ---------------------------------------------------------------------------
__global__ void prep_w(const float* __restrict__ w1, const float* __restrict__ w2,
                       unsigned short* __restrict__ w1f, unsigned short* __restrict__ w2f,
                       float* __restrict__ stats) {
    int tid = blockIdx.x * blockDim.x + threadIdx.x;
    int stride = gridDim.x * blockDim.x;
    if (blockIdx.x == 0 && threadIdx.x < 256) stats[threadIdx.x] = 0.f;
    const int total1 = 7 * 4 * 64 * 8;
    for (int idx = tid; idx < total1; idx += stride) {
        int j = idx & 7, l = (idx >> 3) & 63, t = (idx >> 9) & 3, cc = idx >> 11;
        int o = t * 16 + (l & 15);
        int kk = (l >> 4) * 8 + j;
        w1f[idx] = f2bf(w1[o * 224 + kk * 7 + cc]);
    }
    const int total2 = 14 * 4 * 64 * 8;
    for (int idx = tid; idx < total2; idx += stride) {
        int j = idx & 7, l = (idx >> 3) & 63, t = (idx >> 9) & 3, cc = idx >> 11;
        int o = t * 16 + (l & 15);
        int kk = (l >> 4) * 8 + j;
        int k = cc >> 1, ch = cc & 1;
        int c = ch * 32 + kk;
        w2f[idx] = f2bf(w2[o * 448 + c * 7 + k]);
    }
}

// ---------------------------------------------------------------------------
// Transpose x (512 rows x VFINE) f32 -> xt[v][512] bf16.
// 64-vertex tile, two 256-channel phases. LDS [64 verts][258 u16] (33KB):
//   write: scalar u16 per loaded element, <=2-way banked (stride 258 u16);
//   read:  u16x4 per lane, 64 lanes = one vertex's 512B contiguous store.
// ---------------------------------------------------------------------------
__global__ __launch_bounds__(256) void transpose_x(const float* __restrict__ x,
                                                   unsigned short* __restrict__ xt, int vf) {
    __shared__ __align__(16) unsigned short lds[64 * 258];
    const int t = threadIdx.x;
    const int v0 = blockIdx.x * 64;
    const int j  = t & 15;        // load phase: vert group (4 verts)
    const int r0 = t >> 4;        // load phase: row base
    const int lane = t & 63;
    const int wid = t >> 6;

#pragma unroll
    for (int p = 0; p < 2; ++p) {
        if (p) __syncthreads();
        // ---- load: rows p*256 .. p*256+255; f32x4 per lane (256B/16-lane row)
#pragma unroll
        for (int it = 0; it < 16; ++it) {
            int r = r0 + it * 16;          // row within phase 0..255
            int row = p * 256 + r;
            int vg = v0 + 4 * j;
            f32x4 d = {0.f, 0.f, 0.f, 0.f};
            if (vg + 3 < vf) {
                d = *reinterpret_cast<const f32x4*>(x + (size_t)row * vf + vg);
            } else {
#pragma unroll
                for (int q = 0; q < 4; ++q)
                    if (vg + q < vf) d[q] = x[(size_t)row * vf + vg + q];
            }
#pragma unroll
            for (int q = 0; q < 4; ++q)
                lds[(4 * j + q) * 258 + r] = f2bf(d[q]);
        }
        __syncthreads();
        // ---- store: one vertex per wave instruction, 512B contiguous
#pragma unroll
        for (int i = 0; i < 16; ++i) {
            int v = wid * 16 + i;
            u16x4 o = *reinterpret_cast<const u16x4*>(lds + v * 258 + 4 * lane);
            if (v0 + v < vf)
                *reinterpret_cast<u16x4*>(xt + (size_t)(v0 + v) * 512 + p * 256 + 4 * lane) = o;
        }
    }
}

// ---------------------------------------------------------------------------
// Pool: xp[v][b][c] = mean_k xt[dn[v][k]][b][c]. One wave per coarse vertex.
// ---------------------------------------------------------------------------
__global__ __launch_bounds__(256) void pool_k(const unsigned short* __restrict__ xt,
                                              const int* __restrict__ dn,
                                              unsigned short* __restrict__ xp, int vc) {
    int wid = (blockIdx.x * blockDim.x + threadIdx.x) >> 6;
    int lane = threadIdx.x & 63;
    if (wid >= vc) return;
    float acc[8];
#pragma unroll
    for (int j = 0; j < 8; ++j) acc[j] = 0.f;
#pragma unroll
    for (int k = 0; k < 7; ++k) {
        int n = dn[(size_t)wid * 7 + k];
        short8 d = *reinterpret_cast<const short8*>(xt + (size_t)n * 512 + lane * 8);
#pragma unroll
        for (int j = 0; j < 8; ++j) acc[j] += bf2f((unsigned short)d[j]);
    }
    short8 o;
#pragma unroll
    for (int j = 0; j < 8; ++j) o[j] = (short)f2bf(acc[j] * (1.f / 7.f));
    *reinterpret_cast<short8*>(xp + (size_t)wid * 512 + lane * 8) = o;
}

// ---------------------------------------------------------------------------
// Gathered conv via MFMA 16x16x32 bf16. Per wave: 4 vertices, 64x16 output each.
// xin: [vc][16][32*CCH] bf16; hout: [vc][16][64] bf16 (pre-BN); stats: sum[64],sumsq[64]
// BN_IN: apply BN1(scale/shift from bnp) + LeakyReLU to input elements on load.
// ---------------------------------------------------------------------------
template <int CCH, bool BN_IN>
__global__ __launch_bounds__(256) void conv_mfma(const unsigned short* __restrict__ xin,
                                                 const int* __restrict__ neigh,
                                                 const unsigned short* __restrict__ wfrag,
                                                 const float* __restrict__ bnp,
                                                 unsigned short* __restrict__ hout,
                                                 float* __restrict__ stats,
                                                 int vc, int ngroups) {
    constexpr int C = 32 * CCH;
    constexpr int NCHUNK = 7 * CCH;
    __shared__ __align__(16) unsigned short wlds[NCHUNK * 4 * 64 * 8];
    __shared__ float bsum[128];
    for (int i = threadIdx.x; i < NCHUNK * 256; i += 256)
        reinterpret_cast<short8*>(wlds)[i] = reinterpret_cast<const short8*>(wfrag)[i];
    if (threadIdx.x < 128) bsum[threadIdx.x] = 0.f;
    __syncthreads();

    const int wid = threadIdx.x >> 6;
    const int lane = threadIdx.x & 63;
    const int lb = lane & 15, lg = lane >> 4;

    // BN1 params for the channels this lane loads: c = ch*32 + lg*8 + j
    float scv[CCH][8], shv[CCH][8];
    if constexpr (BN_IN) {
#pragma unroll
        for (int ch = 0; ch < CCH; ++ch)
#pragma unroll
            for (int j = 0; j < 8; ++j) {
                scv[ch][j] = bnp[ch * 32 + lg * 8 + j];
                shv[ch][j] = bnp[64 + ch * 32 + lg * 8 + j];
            }
    }

    float ssum[16], ssq[16];
#pragma unroll
    for (int i = 0; i < 16; ++i) { ssum[i] = 0.f; ssq[i] = 0.f; }

    for (int grp = blockIdx.x; grp < ngroups; grp += gridDim.x) {
        const int v0 = grp * 16 + wid * 4;
        f32x4 acc[4][4];
#pragma unroll
        for (int i = 0; i < 4; ++i)
#pragma unroll
            for (int t = 0; t < 4; ++t) acc[i][t] = (f32x4){0.f, 0.f, 0.f, 0.f};

        auto do_k = [&](int k) {
            int n[4];
#pragma unroll
            for (int i = 0; i < 4; ++i) {
                int v = v0 + i;
                n[i] = (v < vc) ? neigh[(size_t)v * 7 + k] : 0;
            }
#pragma unroll
            for (int ch = 0; ch < CCH; ++ch) {
                const int chunk = k * CCH + ch;
                const short8* wp = reinterpret_cast<const short8*>(wlds) + (chunk * 4) * 64 + lane;
                short8 a0 = wp[0];
                short8 a1 = wp[64];
                short8 a2 = wp[128];
                short8 a3 = wp[192];
#pragma unroll
                for (int i = 0; i < 4; ++i) {
                    short8 b = *reinterpret_cast<const short8*>(
                        xin + (size_t)n[i] * (16 * C) + lb * C + ch * 32 + lg * 8);
                    if constexpr (BN_IN) {
                        short8 bb;
#pragma unroll
                        for (int j = 0; j < 8; ++j) {
                            float z = fmaf(scv[ch][j], bf2f((unsigned short)b[j]), shv[ch][j]);
                            z = fmaxf(z, 0.2f * z);
                            bb[j] = (short)f2bf(z);
                        }
                        b = bb;
                    }
                    acc[i][0] = __builtin_amdgcn_mfma_f32_16x16x32_bf16(a0, b, acc[i][0], 0, 0, 0);
                    acc[i][1] = __builtin_amdgcn_mfma_f32_16x16x32_bf16(a1, b, acc[i][1], 0, 0, 0);
                    acc[i][2] = __builtin_amdgcn_mfma_f32_16x16x32_bf16(a2, b, acc[i][2], 0, 0, 0);
                    acc[i][3] = __builtin_amdgcn_mfma_f32_16x16x32_bf16(a3, b, acc[i][3], 0, 0, 0);
                }
            }
        };
        if constexpr (BN_IN) {
#pragma unroll 2
            for (int k = 0; k < 7; ++k) do_k(k);
        } else {
#pragma unroll 1
            for (int k = 0; k < 7; ++k) do_k(k);
        }

        // epilogue: D[o][b], o = t*16 + lg*4 + r, b = lb
#pragma unroll
        for (int i = 0; i < 4; ++i) {
            const int v = v0 + i;
            if (v < vc) {
#pragma unroll
                for (int t = 0; t < 4; ++t) {
                    u16x4 st;
#pragma unroll
                    for (int r = 0; r < 4; ++r) {
                        float f = acc[i][t][r];
                        ssum[t * 4 + r] += f;
                        ssq[t * 4 + r] += f * f;
                        st[r] = f2bf(f);
                    }
                    *reinterpret_cast<u16x4*>(hout + (size_t)v * 1024 + lb * 64 + t * 16 + lg * 4) = st;
                }
            }
        }
    }
    // reduce over the 16 batch lanes
#pragma unroll
    for (int m = 1; m <= 8; m <<= 1) {
#pragma unroll
        for (int i = 0; i < 16; ++i) {
            ssum[i] += __shfl_xor(ssum[i], m, 64);
            ssq[i] += __shfl_xor(ssq[i], m, 64);
        }
    }
    if (lb == 0) {
#pragma unroll
        for (int t = 0; t < 4; ++t)
#pragma unroll
            for (int r = 0; r < 4; ++r) {
                int o = t * 16 + lg * 4 + r;
                atomicAdd(&bsum[o], ssum[t * 4 + r]);
                atomicAdd(&bsum[64 + o], ssq[t * 4 + r]);
            }
    }
    __syncthreads();
    if (threadIdx.x < 128) atomicAdd(&stats[threadIdx.x], bsum[threadIdx.x]);
}

// ---------------------------------------------------------------------------
// BN params: scale = gamma * rsqrt(var+eps); shift = beta - mean*scale
// ---------------------------------------------------------------------------
__global__ void bn_params(const float* __restrict__ stats, const float* __restrict__ gamma,
                          const float* __restrict__ beta, float* __restrict__ params, float inv_n) {
    int o = threadIdx.x;
    if (o < 64) {
        float mean = stats[o] * inv_n;
        float var = stats[64 + o] * inv_n - mean * mean;
        float sc = gamma[o] * rsqrtf(var + 1e-5f);
        params[o] = sc;
        params[64 + o] = beta[o] - mean * sc;
    }
}

// ---------------------------------------------------------------------------
// Final: BN2+LReLU on h2[v][b][o] bf16, transpose -> out[b][o][v] f32 via LDS
// ---------------------------------------------------------------------------
__global__ __launch_bounds__(256) void final_out(const unsigned short* __restrict__ h2,
                                                 const float* __restrict__ params,
                                                 float* __restrict__ out, int vc) {
    __shared__ float lds[128 * 65];
    const int t = threadIdx.x;
    const int v0 = blockIdx.x * 64;
    const int sub = t & 15, vloc = t >> 4;
    const int o0 = (sub & 7) * 8;
    float sc[8], sh[8];
#pragma unroll
    for (int j = 0; j < 8; ++j) { sc[j] = params[o0 + j]; sh[j] = params[64 + o0 + j]; }
    for (int c = 0; c < 8; ++c) {
        if (c) __syncthreads();
#pragma unroll
        for (int i = 0; i < 4; ++i) {
            int v = v0 + vloc + 16 * i;
            short8 d = {0, 0, 0, 0, 0, 0, 0, 0};
            if (v < vc)
                d = *reinterpret_cast<const short8*>(h2 + (size_t)v * 1024 + c * 128 + sub * 8);
#pragma unroll
            for (int j = 0; j < 8; ++j) {
                float y = sc[j] * bf2f((unsigned short)d[j]) + sh[j];
                y = fmaxf(y, 0.2f * y);
                lds[(sub * 8 + j) * 65 + vloc + 16 * i] = y;
            }
        }
        __syncthreads();
        // 16B f32x4 stores: wave covers 4 rows x 256B contiguous
#pragma unroll
        for (int q = 0; q < 8; ++q) {
            int idx = t + 256 * q;       // 0..2047
            int r = idx >> 4;            // 0..127
            int vq = (idx & 15) * 4;
            int v = v0 + vq;
            const float* lp = lds + r * 65 + vq;
            if (v + 3 < vc) {
                f32x4 o = {lp[0], lp[1], lp[2], lp[3]};
                *reinterpret_cast<f32x4*>(out + (size_t)(c * 128 + r) * vc + v) = o;
            } else {
#pragma unroll
                for (int e = 0; e < 4; ++e)
                    if (v + e < vc) out[(size_t)(c * 128 + r) * vc + v + e] = lp[e];
            }
        }
    }
}

// ---------------------------------------------------------------------------
extern "C" void kernel_launch(void* const* d_in, const int* in_sizes, int n_in,
                              void* d_out, int out_size, void* d_ws, size_t ws_size,
                              hipStream_t stream) {
    const float* x   = (const float*)d_in[0];
    const float* w1  = (const float*)d_in[1];
    const float* g1  = (const float*)d_in[3];
    const float* be1 = (const float*)d_in[4];
    const float* w2  = (const float*)d_in[5];
    const float* g2  = (const float*)d_in[7];
    const float* be2 = (const float*)d_in[8];
    const int* cn    = (const int*)d_in[9];
    const int* dn    = (const int*)d_in[10];
    float* out = (float*)d_out;

    // workspace layout (needs ~210 MB)
    char* ws = (char*)d_ws;
    size_t off = 0;
    auto take = [&](size_t bytes) { size_t o = off; off = (off + bytes + 255) & ~(size_t)255; return o; };
    unsigned short* xp  = (unsigned short*)(ws + take((size_t)VC * 512 * 2));
    unsigned short* h1  = (unsigned short*)(ws + take((size_t)VC * 1024 * 2));
    unsigned short* h2  = (unsigned short*)(ws + take((size_t)VC * 1024 * 2));
    unsigned short* w1f = (unsigned short*)(ws + take(7 * 4 * 64 * 8 * 2));
    unsigned short* w2f = (unsigned short*)(ws + take(14 * 4 * 64 * 8 * 2));
    float* stats        = (float*)(ws + take(256 * 4));       // [sum1|sq1|sum2|sq2]
    float* params       = (float*)(ws + take(256 * 4));       // [sc1|sh1|sc2|sh2]

    // xt (bf16 transposed fine grid) lives in d_out as scratch (dead before final_out)
    unsigned short* xt = (unsigned short*)d_out;

    const float inv_n = 1.0f / (16.0f * (float)VC);
    const int ngroups = (VC + 15) / 16;

    prep_w<<<32, 256, 0, stream>>>(w1, w2, w1f, w2f, stats);
    transpose_x<<<(VFINE + 63) / 64, 256, 0, stream>>>(x, xt, VFINE);
    pool_k<<<(VC + 3) / 4, 256, 0, stream>>>(xt, dn, xp, VC);
    conv_mfma<1, false><<<512, 256, 0, stream>>>(xp, cn, w1f, nullptr, h1, stats, VC, ngroups);
    bn_params<<<1, 64, 0, stream>>>(stats, g1, be1, params, inv_n);
    conv_mfma<2, true><<<512, 256, 0, stream>>>(h1, cn, w2f, params, h2, stats + 128, VC, ngroups);
    bn_params<<<1, 64, 0, stream>>>(stats + 128, g2, be2, params + 128, inv_n);
    final_out<<<(VC + 63) / 64, 256, 0, stream>>>(h2, params + 128, out, VC);
}

// Round 4
// 570.281 us; speedup vs baseline: 1.0303x; 1.0303x over previous
//
#include <hip/hip_runtime.h>
#include <hip/hip_bf16.h>

// DownBlock: pool(mean over 7 down-neighbors) -> conv1(K=7, 32->64) -> BN+LReLU
//         -> conv2(K=7, 64->64) -> BN+LReLU
// B=16, C_IN=32, C=64, V_FINE=163842, V=40962, K=7.
// Biases b1/b2 are dead: BN's mean subtraction absorbs per-channel constants.
// Convs are gather-latency-bound => keep conv critical path bare (no BN, no
// stats), cap VGPR at 128 via __launch_bounds__(512,4) for 16 waves/CU.

#define B_SZ     16
#define CIN      32
#define CMID     64
#define VFINE    163842
#define VC       40962
#define KNB      7

typedef __attribute__((ext_vector_type(8))) short  short8;   // 8 x bf16 (as i16)
typedef __attribute__((ext_vector_type(4))) float  f32x4;
typedef __attribute__((ext_vector_type(4))) unsigned short u16x4;

__device__ inline float bf2f(unsigned short u) {
    return __builtin_bit_cast(float, (unsigned int)(((unsigned int)u) << 16));
}
__device__ inline unsigned short f2bf(float f) {
    __hip_bfloat16 h = __float2bfloat16(f);
    return __builtin_bit_cast(unsigned short, h);
}

// ---------------------------------------------------------------------------
// Prep: reorder W into per-lane MFMA A-fragments, bf16. Also zeroes stats.
// Fragment (chunk, otile): lane l, elem j ->  A[o = otile*16 + (l&15)][kk = (l>>4)*8 + j]
// conv1: chunk cc = k (7 chunks), c = kk.        W1[o][c*7+k]
// conv2: chunk cc = k*2 + ch (14), c = ch*32+kk. W2[o][c*7+k]
// ---------------------------------------------------------------------------
__global__ void prep_w(const float* __restrict__ w1, const float* __restrict__ w2,
                       unsigned short* __restrict__ w1f, unsigned short* __restrict__ w2f,
                       float* __restrict__ stats) {
    int tid = blockIdx.x * blockDim.x + threadIdx.x;
    int stride = gridDim.x * blockDim.x;
    if (blockIdx.x == 0 && threadIdx.x < 256) stats[threadIdx.x] = 0.f;
    const int total1 = 7 * 4 * 64 * 8;
    for (int idx = tid; idx < total1; idx += stride) {
        int j = idx & 7, l = (idx >> 3) & 63, t = (idx >> 9) & 3, cc = idx >> 11;
        int o = t * 16 + (l & 15);
        int kk = (l >> 4) * 8 + j;
        w1f[idx] = f2bf(w1[o * 224 + kk * 7 + cc]);
    }
    const int total2 = 14 * 4 * 64 * 8;
    for (int idx = tid; idx < total2; idx += stride) {
        int j = idx & 7, l = (idx >> 3) & 63, t = (idx >> 9) & 3, cc = idx >> 11;
        int o = t * 16 + (l & 15);
        int kk = (l >> 4) * 8 + j;
        int k = cc >> 1, ch = cc & 1;
        int c = ch * 32 + kk;
        w2f[idx] = f2bf(w2[o * 448 + c * 7 + k]);
    }
}

// ---------------------------------------------------------------------------
// Transpose x (512 rows x VFINE) f32 -> xt[v][512] bf16.
// 64-vertex tile, two 256-channel phases. LDS [64 verts][258 u16] (33KB).
// ---------------------------------------------------------------------------
__global__ __launch_bounds__(256) void transpose_x(const float* __restrict__ x,
                                                   unsigned short* __restrict__ xt, int vf) {
    __shared__ __align__(16) unsigned short lds[64 * 258];
    const int t = threadIdx.x;
    const int v0 = blockIdx.x * 64;
    const int j  = t & 15;        // load phase: vert group (4 verts)
    const int r0 = t >> 4;        // load phase: row base
    const int lane = t & 63;
    const int wid = t >> 6;

#pragma unroll
    for (int p = 0; p < 2; ++p) {
        if (p) __syncthreads();
#pragma unroll
        for (int it = 0; it < 16; ++it) {
            int r = r0 + it * 16;          // row within phase 0..255
            int row = p * 256 + r;
            int vg = v0 + 4 * j;
            f32x4 d = {0.f, 0.f, 0.f, 0.f};
            if (vg + 3 < vf) {
                d = *reinterpret_cast<const f32x4*>(x + (size_t)row * vf + vg);
            } else {
#pragma unroll
                for (int q = 0; q < 4; ++q)
                    if (vg + q < vf) d[q] = x[(size_t)row * vf + vg + q];
            }
#pragma unroll
            for (int q = 0; q < 4; ++q)
                lds[(4 * j + q) * 258 + r] = f2bf(d[q]);
        }
        __syncthreads();
#pragma unroll
        for (int i = 0; i < 16; ++i) {
            int v = wid * 16 + i;
            u16x4 o = *reinterpret_cast<const u16x4*>(lds + v * 258 + 4 * lane);
            if (v0 + v < vf)
                *reinterpret_cast<u16x4*>(xt + (size_t)(v0 + v) * 512 + p * 256 + 4 * lane) = o;
        }
    }
}

// ---------------------------------------------------------------------------
// Pool: xp[v][b][c] = mean_k xt[dn[v][k]][b][c]. One wave per coarse vertex.
// ---------------------------------------------------------------------------
__global__ __launch_bounds__(256) void pool_k(const unsigned short* __restrict__ xt,
                                              const int* __restrict__ dn,
                                              unsigned short* __restrict__ xp, int vc) {
    int wid = (blockIdx.x * blockDim.x + threadIdx.x) >> 6;
    int lane = threadIdx.x & 63;
    if (wid >= vc) return;
    float acc[8];
#pragma unroll
    for (int j = 0; j < 8; ++j) acc[j] = 0.f;
#pragma unroll
    for (int k = 0; k < 7; ++k) {
        int n = dn[(size_t)wid * 7 + k];
        short8 d = *reinterpret_cast<const short8*>(xt + (size_t)n * 512 + lane * 8);
#pragma unroll
        for (int j = 0; j < 8; ++j) acc[j] += bf2f((unsigned short)d[j]);
    }
    short8 o;
#pragma unroll
    for (int j = 0; j < 8; ++j) o[j] = (short)f2bf(acc[j] * (1.f / 7.f));
    *reinterpret_cast<short8*>(xp + (size_t)wid * 512 + lane * 8) = o;
}

// ---------------------------------------------------------------------------
// Gathered conv via MFMA 16x16x32 bf16. 512-thread block = 8 waves;
// per wave 4 vertices (block = 32 verts). Weights staged once in LDS.
// VGPR capped at 128 (launch_bounds 512,4) => 16 waves/CU for both convs
// (conv2: 2 blocks x 57KB LDS = 114KB; conv1: VGPR-capped at 2 blocks).
// xin: [vc][16][32*CCH] bf16; hout: [vc][16][64] bf16 (pre-BN).
// ---------------------------------------------------------------------------
template <int CCH>
__global__ __launch_bounds__(512, 4) void conv_mfma(const unsigned short* __restrict__ xin,
                                                    const int* __restrict__ neigh,
                                                    const unsigned short* __restrict__ wfrag,
                                                    unsigned short* __restrict__ hout,
                                                    int vc) {
    constexpr int C = 32 * CCH;
    constexpr int NCHUNK = 7 * CCH;
    __shared__ __align__(16) unsigned short wlds[NCHUNK * 2048];
    for (int i = threadIdx.x; i < NCHUNK * 256; i += 512)
        reinterpret_cast<short8*>(wlds)[i] = reinterpret_cast<const short8*>(wfrag)[i];
    __syncthreads();

    const int wid = threadIdx.x >> 6;
    const int lane = threadIdx.x & 63;
    const int lb = lane & 15, lg = lane >> 4;
    const int v0 = blockIdx.x * 32 + wid * 4;
    const int boff = lb * C + lg * 8;   // per-lane byte-offset part of gather

    f32x4 acc[4][4];
#pragma unroll
    for (int i = 0; i < 4; ++i)
#pragma unroll
        for (int t = 0; t < 4; ++t) acc[i][t] = (f32x4){0.f, 0.f, 0.f, 0.f};

#pragma unroll 1
    for (int k = 0; k < 7; ++k) {
        int n[4];
#pragma unroll
        for (int i = 0; i < 4; ++i) {
            int v = v0 + i;
            n[i] = (v < vc) ? neigh[(size_t)v * 7 + k] : 0;
        }
#pragma unroll
        for (int ch = 0; ch < CCH; ++ch) {
            const int chunk = k * CCH + ch;
            const short8* wp = reinterpret_cast<const short8*>(wlds) + (chunk * 4) * 64 + lane;
            short8 a0 = wp[0];
            short8 a1 = wp[64];
            short8 a2 = wp[128];
            short8 a3 = wp[192];
#pragma unroll
            for (int i = 0; i < 4; ++i) {
                const short8 b = *reinterpret_cast<const short8*>(
                    xin + (size_t)n[i] * (16 * C) + boff + ch * 32);
                acc[i][0] = __builtin_amdgcn_mfma_f32_16x16x32_bf16(a0, b, acc[i][0], 0, 0, 0);
                acc[i][1] = __builtin_amdgcn_mfma_f32_16x16x32_bf16(a1, b, acc[i][1], 0, 0, 0);
                acc[i][2] = __builtin_amdgcn_mfma_f32_16x16x32_bf16(a2, b, acc[i][2], 0, 0, 0);
                acc[i][3] = __builtin_amdgcn_mfma_f32_16x16x32_bf16(a3, b, acc[i][3], 0, 0, 0);
            }
        }
    }
    // epilogue: D[o][b], o = t*16 + lg*4 + r, b = lb
#pragma unroll
    for (int i = 0; i < 4; ++i) {
        const int v = v0 + i;
        if (v < vc) {
#pragma unroll
            for (int t = 0; t < 4; ++t) {
                u16x4 st;
#pragma unroll
                for (int r = 0; r < 4; ++r) st[r] = f2bf(acc[i][t][r]);
                *reinterpret_cast<u16x4*>(hout + (size_t)v * 1024 + lb * 64 + t * 16 + lg * 4) = st;
            }
        }
    }
}

// ---------------------------------------------------------------------------
// Stats: sum/sumsq per channel over h[v][b][64]. Grid-stride, short8 loads.
// ---------------------------------------------------------------------------
__global__ __launch_bounds__(256) void stats_k(const unsigned short* __restrict__ h,
                                               float* __restrict__ stats, int total8) {
    __shared__ float bsum[128];
    if (threadIdx.x < 128) bsum[threadIdx.x] = 0.f;
    __syncthreads();
    const int lane = threadIdx.x & 63;
    int idx0 = blockIdx.x * blockDim.x + threadIdx.x;
    int stride = gridDim.x * blockDim.x;          // multiple of 8
    const int c0 = (idx0 & 7) * 8;
    float s[8], q[8];
#pragma unroll
    for (int j = 0; j < 8; ++j) { s[j] = 0.f; q[j] = 0.f; }
    for (int idx = idx0; idx < total8; idx += stride) {
        short8 d = *reinterpret_cast<const short8*>(h + (size_t)idx * 8);
#pragma unroll
        for (int j = 0; j < 8; ++j) {
            float f = bf2f((unsigned short)d[j]);
            s[j] += f;
            q[j] += f * f;
        }
    }
#pragma unroll
    for (int m = 8; m <= 32; m <<= 1) {
#pragma unroll
        for (int j = 0; j < 8; ++j) {
            s[j] += __shfl_xor(s[j], m, 64);
            q[j] += __shfl_xor(q[j], m, 64);
        }
    }
    if (lane < 8) {
#pragma unroll
        for (int j = 0; j < 8; ++j) {
            atomicAdd(&bsum[c0 + j], s[j]);
            atomicAdd(&bsum[64 + c0 + j], q[j]);
        }
    }
    __syncthreads();
    if (threadIdx.x < 128) atomicAdd(&stats[threadIdx.x], bsum[threadIdx.x]);
}

// ---------------------------------------------------------------------------
// BN params: scale = gamma * rsqrt(var+eps); shift = beta - mean*scale
// ---------------------------------------------------------------------------
__global__ void bn_params(const float* __restrict__ stats, const float* __restrict__ gamma,
                          const float* __restrict__ beta, float* __restrict__ params, float inv_n) {
    int o = threadIdx.x;
    if (o < 64) {
        float mean = stats[o] * inv_n;
        float var = stats[64 + o] * inv_n - mean * mean;
        float sc = gamma[o] * rsqrtf(var + 1e-5f);
        params[o] = sc;
        params[64 + o] = beta[o] - mean * sc;
    }
}

// ---------------------------------------------------------------------------
// BN+LReLU apply in-place on h ([v][b][64] bf16)
// ---------------------------------------------------------------------------
__global__ __launch_bounds__(256) void bn_apply(unsigned short* __restrict__ h,
                                                const float* __restrict__ params, int total8) {
    int stride = gridDim.x * blockDim.x;
    int idx0 = blockIdx.x * blockDim.x + threadIdx.x;
    int c0 = (idx0 & 7) * 8;
    float sc[8], sh[8];
#pragma unroll
    for (int j = 0; j < 8; ++j) { sc[j] = params[c0 + j]; sh[j] = params[64 + c0 + j]; }
    for (int idx = idx0; idx < total8; idx += stride) {
        short8 d = *reinterpret_cast<const short8*>(h + (size_t)idx * 8);
        short8 o;
#pragma unroll
        for (int j = 0; j < 8; ++j) {
            float y = sc[j] * bf2f((unsigned short)d[j]) + sh[j];
            y = fmaxf(y, 0.2f * y);
            o[j] = (short)f2bf(y);
        }
        *reinterpret_cast<short8*>(h + (size_t)idx * 8) = o;
    }
}

// ---------------------------------------------------------------------------
// Final: BN2+LReLU on h2[v][b][o] bf16, transpose -> out[b][o][v] f32 via LDS
// ---------------------------------------------------------------------------
__global__ __launch_bounds__(256) void final_out(const unsigned short* __restrict__ h2,
                                                 const float* __restrict__ params,
                                                 float* __restrict__ out, int vc) {
    __shared__ float lds[128 * 65];
    const int t = threadIdx.x;
    const int v0 = blockIdx.x * 64;
    const int sub = t & 15, vloc = t >> 4;
    const int o0 = (sub & 7) * 8;
    float sc[8], sh[8];
#pragma unroll
    for (int j = 0; j < 8; ++j) { sc[j] = params[o0 + j]; sh[j] = params[64 + o0 + j]; }
    for (int c = 0; c < 8; ++c) {
        if (c) __syncthreads();
#pragma unroll
        for (int i = 0; i < 4; ++i) {
            int v = v0 + vloc + 16 * i;
            short8 d = {0, 0, 0, 0, 0, 0, 0, 0};
            if (v < vc)
                d = *reinterpret_cast<const short8*>(h2 + (size_t)v * 1024 + c * 128 + sub * 8);
#pragma unroll
            for (int j = 0; j < 8; ++j) {
                float y = sc[j] * bf2f((unsigned short)d[j]) + sh[j];
                y = fmaxf(y, 0.2f * y);
                lds[(sub * 8 + j) * 65 + vloc + 16 * i] = y;
            }
        }
        __syncthreads();
#pragma unroll
        for (int q = 0; q < 8; ++q) {
            int idx = t + 256 * q;       // 0..2047
            int r = idx >> 4;            // 0..127
            int vq = (idx & 15) * 4;
            int v = v0 + vq;
            const float* lp = lds + r * 65 + vq;
            if (v + 3 < vc) {
                f32x4 o = {lp[0], lp[1], lp[2], lp[3]};
                *reinterpret_cast<f32x4*>(out + (size_t)(c * 128 + r) * vc + v) = o;
            } else {
#pragma unroll
                for (int e = 0; e < 4; ++e)
                    if (v + e < vc) out[(size_t)(c * 128 + r) * vc + v + e] = lp[e];
            }
        }
    }
}

// ---------------------------------------------------------------------------
extern "C" void kernel_launch(void* const* d_in, const int* in_sizes, int n_in,
                              void* d_out, int out_size, void* d_ws, size_t ws_size,
                              hipStream_t stream) {
    const float* x   = (const float*)d_in[0];
    const float* w1  = (const float*)d_in[1];
    const float* g1  = (const float*)d_in[3];
    const float* be1 = (const float*)d_in[4];
    const float* w2  = (const float*)d_in[5];
    const float* g2  = (const float*)d_in[7];
    const float* be2 = (const float*)d_in[8];
    const int* cn    = (const int*)d_in[9];
    const int* dn    = (const int*)d_in[10];
    float* out = (float*)d_out;

    // workspace layout (~210 MB)
    char* ws = (char*)d_ws;
    size_t off = 0;
    auto take = [&](size_t bytes) { size_t o = off; off = (off + bytes + 255) & ~(size_t)255; return o; };
    unsigned short* xp  = (unsigned short*)(ws + take((size_t)VC * 512 * 2));
    unsigned short* h1  = (unsigned short*)(ws + take((size_t)VC * 1024 * 2));
    unsigned short* h2  = (unsigned short*)(ws + take((size_t)VC * 1024 * 2));
    unsigned short* w1f = (unsigned short*)(ws + take(7 * 4 * 64 * 8 * 2));
    unsigned short* w2f = (unsigned short*)(ws + take(14 * 4 * 64 * 8 * 2));
    float* stats        = (float*)(ws + take(256 * 4));       // [sum1|sq1|sum2|sq2]
    float* params       = (float*)(ws + take(256 * 4));       // [sc1|sh1|sc2|sh2]

    // xt (bf16 transposed fine grid) lives in d_out as scratch (dead before final_out)
    unsigned short* xt = (unsigned short*)d_out;

    const float inv_n = 1.0f / (16.0f * (float)VC);
    const int nblk2 = (VC + 31) / 32;   // 32 verts per 512-thread conv block

    prep_w<<<32, 256, 0, stream>>>(w1, w2, w1f, w2f, stats);
    transpose_x<<<(VFINE + 63) / 64, 256, 0, stream>>>(x, xt, VFINE);
    pool_k<<<(VC + 3) / 4, 256, 0, stream>>>(xt, dn, xp, VC);
    conv_mfma<1><<<nblk2, 512, 0, stream>>>(xp, cn, w1f, h1, VC);
    stats_k<<<2048, 256, 0, stream>>>(h1, stats, VC * 128);
    bn_params<<<1, 64, 0, stream>>>(stats, g1, be1, params, inv_n);
    bn_apply<<<2048, 256, 0, stream>>>(h1, params, VC * 128);
    conv_mfma<2><<<nblk2, 512, 0, stream>>>(h1, cn, w2f, h2, VC);
    stats_k<<<2048, 256, 0, stream>>>(h2, stats + 128, VC * 128);
    bn_params<<<1, 64, 0, stream>>>(stats + 128, g2, be2, params + 128, inv_n);
    final_out<<<(VC + 63) / 64, 256, 0, stream>>>(h2, params + 128, out, VC);
}

// Round 5
// 483.143 us; speedup vs baseline: 1.2161x; 1.1804x over previous
//
#include <hip/hip_runtime.h>
#include <hip/hip_bf16.h>

// DownBlock: pool(mean over 7 down-neighbors) -> conv1(K=7, 32->64) -> BN+LReLU
//         -> conv2(K=7, 64->64) -> BN+LReLU
// B=16, C_IN=32, C=64, V_FINE=163842, V=40962, K=7.
// Biases b1/b2 are dead: BN's mean subtraction absorbs per-channel constants.
// Convs: 512-thread blocks, launch_bounds(512,4) => <=128 VGPR, 16 waves/CU.
// BN stats fused in conv epilogue (post-k-loop registers only, ~free).

#define B_SZ     16
#define CIN      32
#define CMID     64
#define VFINE    163842
#define VC       40962
#define KNB      7

typedef __attribute__((ext_vector_type(8))) short  short8;   // 8 x bf16 (as i16)
typedef __attribute__((ext_vector_type(4))) float  f32x4;
typedef __attribute__((ext_vector_type(4))) unsigned short u16x4;

__device__ inline float bf2f(unsigned short u) {
    return __builtin_bit_cast(float, (unsigned int)(((unsigned int)u) << 16));
}
__device__ inline unsigned short f2bf(float f) {
    __hip_bfloat16 h = __float2bfloat16(f);
    return __builtin_bit_cast(unsigned short, h);
}

// ---------------------------------------------------------------------------
// Prep: reorder W into per-lane MFMA A-fragments, bf16. Also zeroes stats.
// Fragment (chunk, otile): lane l, elem j ->  A[o = otile*16 + (l&15)][kk = (l>>4)*8 + j]
// conv1: chunk cc = k (7 chunks), c = kk.        W1[o][c*7+k]
// conv2: chunk cc = k*2 + ch (14), c = ch*32+kk. W2[o][c*7+k]
// ---------------------------------------------------------------------------
__global__ void prep_w(const float* __restrict__ w1, const float* __restrict__ w2,
                       unsigned short* __restrict__ w1f, unsigned short* __restrict__ w2f,
                       float* __restrict__ stats) {
    int tid = blockIdx.x * blockDim.x + threadIdx.x;
    int stride = gridDim.x * blockDim.x;
    if (blockIdx.x == 0 && threadIdx.x < 256) stats[threadIdx.x] = 0.f;
    const int total1 = 7 * 4 * 64 * 8;
    for (int idx = tid; idx < total1; idx += stride) {
        int j = idx & 7, l = (idx >> 3) & 63, t = (idx >> 9) & 3, cc = idx >> 11;
        int o = t * 16 + (l & 15);
        int kk = (l >> 4) * 8 + j;
        w1f[idx] = f2bf(w1[o * 224 + kk * 7 + cc]);
    }
    const int total2 = 14 * 4 * 64 * 8;
    for (int idx = tid; idx < total2; idx += stride) {
        int j = idx & 7, l = (idx >> 3) & 63, t = (idx >> 9) & 3, cc = idx >> 11;
        int o = t * 16 + (l & 15);
        int kk = (l >> 4) * 8 + j;
        int k = cc >> 1, ch = cc & 1;
        int c = ch * 32 + kk;
        w2f[idx] = f2bf(w2[o * 448 + c * 7 + k]);
    }
}

// ---------------------------------------------------------------------------
// Transpose x (512 rows x VFINE) f32 -> xt[v][512] bf16.
// 64-vertex tile, two 256-channel phases. LDS [64 verts][258 u16] (33KB).
// ---------------------------------------------------------------------------
__global__ __launch_bounds__(256) void transpose_x(const float* __restrict__ x,
                                                   unsigned short* __restrict__ xt, int vf) {
    __shared__ __align__(16) unsigned short lds[64 * 258];
    const int t = threadIdx.x;
    const int v0 = blockIdx.x * 64;
    const int j  = t & 15;        // load phase: vert group (4 verts)
    const int r0 = t >> 4;        // load phase: row base
    const int lane = t & 63;
    const int wid = t >> 6;

#pragma unroll
    for (int p = 0; p < 2; ++p) {
        if (p) __syncthreads();
#pragma unroll
        for (int it = 0; it < 16; ++it) {
            int r = r0 + it * 16;          // row within phase 0..255
            int row = p * 256 + r;
            int vg = v0 + 4 * j;
            f32x4 d = {0.f, 0.f, 0.f, 0.f};
            if (vg + 3 < vf) {
                d = *reinterpret_cast<const f32x4*>(x + (size_t)row * vf + vg);
            } else {
#pragma unroll
                for (int q = 0; q < 4; ++q)
                    if (vg + q < vf) d[q] = x[(size_t)row * vf + vg + q];
            }
#pragma unroll
            for (int q = 0; q < 4; ++q)
                lds[(4 * j + q) * 258 + r] = f2bf(d[q]);
        }
        __syncthreads();
#pragma unroll
        for (int i = 0; i < 16; ++i) {
            int v = wid * 16 + i;
            u16x4 o = *reinterpret_cast<const u16x4*>(lds + v * 258 + 4 * lane);
            if (v0 + v < vf)
                *reinterpret_cast<u16x4*>(xt + (size_t)(v0 + v) * 512 + p * 256 + 4 * lane) = o;
        }
    }
}

// ---------------------------------------------------------------------------
// Pool: xp[v][b][c] = mean_k xt[dn[v][k]][b][c]. One wave per coarse vertex.
// ---------------------------------------------------------------------------
__global__ __launch_bounds__(256) void pool_k(const unsigned short* __restrict__ xt,
                                              const int* __restrict__ dn,
                                              unsigned short* __restrict__ xp, int vc) {
    int wid = (blockIdx.x * blockDim.x + threadIdx.x) >> 6;
    int lane = threadIdx.x & 63;
    if (wid >= vc) return;
    float acc[8];
#pragma unroll
    for (int j = 0; j < 8; ++j) acc[j] = 0.f;
#pragma unroll
    for (int k = 0; k < 7; ++k) {
        int n = __builtin_amdgcn_readfirstlane(dn[(size_t)wid * 7 + k]);
        short8 d = *reinterpret_cast<const short8*>(xt + (size_t)n * 512 + lane * 8);
#pragma unroll
        for (int j = 0; j < 8; ++j) acc[j] += bf2f((unsigned short)d[j]);
    }
    short8 o;
#pragma unroll
    for (int j = 0; j < 8; ++j) o[j] = (short)f2bf(acc[j] * (1.f / 7.f));
    *reinterpret_cast<short8*>(xp + (size_t)wid * 512 + lane * 8) = o;
}

// ---------------------------------------------------------------------------
// Gathered conv via MFMA 16x16x32 bf16. 512-thread block = 8 waves;
// per wave 4 vertices (block = 32 verts). Weights staged once in LDS.
// Neighbor indices wave-uniform via readfirstlane => SGPR gather bases.
// BN stats (sum/sumsq per channel) fused in epilogue.
// xin: [vc][16][32*CCH] bf16; hout: [vc][16][64] bf16 (pre-BN).
// ---------------------------------------------------------------------------
template <int CCH>
__global__ __launch_bounds__(512, 4) void conv_mfma(const unsigned short* __restrict__ xin,
                                                    const int* __restrict__ neigh,
                                                    const unsigned short* __restrict__ wfrag,
                                                    unsigned short* __restrict__ hout,
                                                    float* __restrict__ stats,
                                                    int vc) {
    constexpr int C = 32 * CCH;
    constexpr int NCHUNK = 7 * CCH;
    __shared__ __align__(16) unsigned short wlds[NCHUNK * 2048];
    __shared__ float bsum[128];
    for (int i = threadIdx.x; i < NCHUNK * 256; i += 512)
        reinterpret_cast<short8*>(wlds)[i] = reinterpret_cast<const short8*>(wfrag)[i];
    if (threadIdx.x < 128) bsum[threadIdx.x] = 0.f;
    __syncthreads();

    const int wid = threadIdx.x >> 6;
    const int lane = threadIdx.x & 63;
    const int lb = lane & 15, lg = lane >> 4;
    const int v0 = blockIdx.x * 32 + wid * 4;
    const int boff = lb * C + lg * 8;   // per-lane element offset within vertex block

    f32x4 acc[4][4];
#pragma unroll
    for (int i = 0; i < 4; ++i)
#pragma unroll
        for (int t = 0; t < 4; ++t) acc[i][t] = (f32x4){0.f, 0.f, 0.f, 0.f};

#pragma unroll 1
    for (int k = 0; k < 7; ++k) {
        int n[4];
#pragma unroll
        for (int i = 0; i < 4; ++i) {
            int v = v0 + i;
            n[i] = __builtin_amdgcn_readfirstlane((v < vc) ? neigh[(size_t)v * 7 + k] : 0);
        }
#pragma unroll
        for (int ch = 0; ch < CCH; ++ch) {
            const int chunk = k * CCH + ch;
            const short8* wp = reinterpret_cast<const short8*>(wlds) + (chunk * 4) * 64 + lane;
            short8 a0 = wp[0];
            short8 a1 = wp[64];
            short8 a2 = wp[128];
            short8 a3 = wp[192];
#pragma unroll
            for (int i = 0; i < 4; ++i) {
                const short8 b = *reinterpret_cast<const short8*>(
                    xin + (size_t)n[i] * (16 * C) + boff + ch * 32);
                acc[i][0] = __builtin_amdgcn_mfma_f32_16x16x32_bf16(a0, b, acc[i][0], 0, 0, 0);
                acc[i][1] = __builtin_amdgcn_mfma_f32_16x16x32_bf16(a1, b, acc[i][1], 0, 0, 0);
                acc[i][2] = __builtin_amdgcn_mfma_f32_16x16x32_bf16(a2, b, acc[i][2], 0, 0, 0);
                acc[i][3] = __builtin_amdgcn_mfma_f32_16x16x32_bf16(a3, b, acc[i][3], 0, 0, 0);
            }
        }
    }

    // epilogue: D[o][b], o = t*16 + lg*4 + r, b = lb. Stats live only here.
    float ssum[16], ssq[16];
#pragma unroll
    for (int i = 0; i < 16; ++i) { ssum[i] = 0.f; ssq[i] = 0.f; }
#pragma unroll
    for (int i = 0; i < 4; ++i) {
        const int v = v0 + i;
        if (v < vc) {
#pragma unroll
            for (int t = 0; t < 4; ++t) {
                u16x4 st;
#pragma unroll
                for (int r = 0; r < 4; ++r) {
                    float f = acc[i][t][r];
                    ssum[t * 4 + r] += f;
                    ssq[t * 4 + r] += f * f;
                    st[r] = f2bf(f);
                }
                *reinterpret_cast<u16x4*>(hout + (size_t)v * 1024 + lb * 64 + t * 16 + lg * 4) = st;
            }
        }
    }
    // reduce over the 16 batch lanes
#pragma unroll
    for (int m = 1; m <= 8; m <<= 1) {
#pragma unroll
        for (int i = 0; i < 16; ++i) {
            ssum[i] += __shfl_xor(ssum[i], m, 64);
            ssq[i] += __shfl_xor(ssq[i], m, 64);
        }
    }
    if (lb == 0) {
#pragma unroll
        for (int t = 0; t < 4; ++t)
#pragma unroll
            for (int r = 0; r < 4; ++r) {
                int o = t * 16 + lg * 4 + r;
                atomicAdd(&bsum[o], ssum[t * 4 + r]);
                atomicAdd(&bsum[64 + o], ssq[t * 4 + r]);
            }
    }
    __syncthreads();
    if (threadIdx.x < 128) atomicAdd(&stats[threadIdx.x], bsum[threadIdx.x]);
}

// ---------------------------------------------------------------------------
// BN params: scale = gamma * rsqrt(var+eps); shift = beta - mean*scale
// ---------------------------------------------------------------------------
__global__ void bn_params(const float* __restrict__ stats, const float* __restrict__ gamma,
                          const float* __restrict__ beta, float* __restrict__ params, float inv_n) {
    int o = threadIdx.x;
    if (o < 64) {
        float mean = stats[o] * inv_n;
        float var = stats[64 + o] * inv_n - mean * mean;
        float sc = gamma[o] * rsqrtf(var + 1e-5f);
        params[o] = sc;
        params[64 + o] = beta[o] - mean * sc;
    }
}

// ---------------------------------------------------------------------------
// BN+LReLU apply in-place on h ([v][b][64] bf16)
// ---------------------------------------------------------------------------
__global__ __launch_bounds__(256) void bn_apply(unsigned short* __restrict__ h,
                                                const float* __restrict__ params, int total8) {
    int stride = gridDim.x * blockDim.x;
    int idx0 = blockIdx.x * blockDim.x + threadIdx.x;
    int c0 = (idx0 & 7) * 8;
    float sc[8], sh[8];
#pragma unroll
    for (int j = 0; j < 8; ++j) { sc[j] = params[c0 + j]; sh[j] = params[64 + c0 + j]; }
    for (int idx = idx0; idx < total8; idx += stride) {
        short8 d = *reinterpret_cast<const short8*>(h + (size_t)idx * 8);
        short8 o;
#pragma unroll
        for (int j = 0; j < 8; ++j) {
            float y = sc[j] * bf2f((unsigned short)d[j]) + sh[j];
            y = fmaxf(y, 0.2f * y);
            o[j] = (short)f2bf(y);
        }
        *reinterpret_cast<short8*>(h + (size_t)idx * 8) = o;
    }
}

// ---------------------------------------------------------------------------
// Final: BN2+LReLU on h2[v][b][o] bf16, transpose -> out[b][o][v] f32 via LDS
// ---------------------------------------------------------------------------
__global__ __launch_bounds__(256) void final_out(const unsigned short* __restrict__ h2,
                                                 const float* __restrict__ params,
                                                 float* __restrict__ out, int vc) {
    __shared__ float lds[128 * 65];
    const int t = threadIdx.x;
    const int v0 = blockIdx.x * 64;
    const int sub = t & 15, vloc = t >> 4;
    const int o0 = (sub & 7) * 8;
    float sc[8], sh[8];
#pragma unroll
    for (int j = 0; j < 8; ++j) { sc[j] = params[o0 + j]; sh[j] = params[64 + o0 + j]; }
    for (int c = 0; c < 8; ++c) {
        if (c) __syncthreads();
#pragma unroll
        for (int i = 0; i < 4; ++i) {
            int v = v0 + vloc + 16 * i;
            short8 d = {0, 0, 0, 0, 0, 0, 0, 0};
            if (v < vc)
                d = *reinterpret_cast<const short8*>(h2 + (size_t)v * 1024 + c * 128 + sub * 8);
#pragma unroll
            for (int j = 0; j < 8; ++j) {
                float y = sc[j] * bf2f((unsigned short)d[j]) + sh[j];
                y = fmaxf(y, 0.2f * y);
                lds[(sub * 8 + j) * 65 + vloc + 16 * i] = y;
            }
        }
        __syncthreads();
#pragma unroll
        for (int q = 0; q < 8; ++q) {
            int idx = t + 256 * q;       // 0..2047
            int r = idx >> 4;            // 0..127
            int vq = (idx & 15) * 4;
            int v = v0 + vq;
            const float* lp = lds + r * 65 + vq;
            if (v + 3 < vc) {
                f32x4 o = {lp[0], lp[1], lp[2], lp[3]};
                *reinterpret_cast<f32x4*>(out + (size_t)(c * 128 + r) * vc + v) = o;
            } else {
#pragma unroll
                for (int e = 0; e < 4; ++e)
                    if (v + e < vc) out[(size_t)(c * 128 + r) * vc + v + e] = lp[e];
            }
        }
    }
}

// ---------------------------------------------------------------------------
extern "C" void kernel_launch(void* const* d_in, const int* in_sizes, int n_in,
                              void* d_out, int out_size, void* d_ws, size_t ws_size,
                              hipStream_t stream) {
    const float* x   = (const float*)d_in[0];
    const float* w1  = (const float*)d_in[1];
    const float* g1  = (const float*)d_in[3];
    const float* be1 = (const float*)d_in[4];
    const float* w2  = (const float*)d_in[5];
    const float* g2  = (const float*)d_in[7];
    const float* be2 = (const float*)d_in[8];
    const int* cn    = (const int*)d_in[9];
    const int* dn    = (const int*)d_in[10];
    float* out = (float*)d_out;

    // workspace layout (~210 MB)
    char* ws = (char*)d_ws;
    size_t off = 0;
    auto take = [&](size_t bytes) { size_t o = off; off = (off + bytes + 255) & ~(size_t)255; return o; };
    unsigned short* xp  = (unsigned short*)(ws + take((size_t)VC * 512 * 2));
    unsigned short* h1  = (unsigned short*)(ws + take((size_t)VC * 1024 * 2));
    unsigned short* h2  = (unsigned short*)(ws + take((size_t)VC * 1024 * 2));
    unsigned short* w1f = (unsigned short*)(ws + take(7 * 4 * 64 * 8 * 2));
    unsigned short* w2f = (unsigned short*)(ws + take(14 * 4 * 64 * 8 * 2));
    float* stats        = (float*)(ws + take(256 * 4));       // [sum1|sq1|sum2|sq2]
    float* params       = (float*)(ws + take(256 * 4));       // [sc1|sh1|sc2|sh2]

    // xt (bf16 transposed fine grid) lives in d_out as scratch (dead before final_out)
    unsigned short* xt = (unsigned short*)d_out;

    const float inv_n = 1.0f / (16.0f * (float)VC);
    const int nblk2 = (VC + 31) / 32;   // 32 verts per 512-thread conv block

    prep_w<<<32, 256, 0, stream>>>(w1, w2, w1f, w2f, stats);
    transpose_x<<<(VFINE + 63) / 64, 256, 0, stream>>>(x, xt, VFINE);
    pool_k<<<(VC + 3) / 4, 256, 0, stream>>>(xt, dn, xp, VC);
    conv_mfma<1><<<nblk2, 512, 0, stream>>>(xp, cn, w1f, h1, stats, VC);
    bn_params<<<1, 64, 0, stream>>>(stats, g1, be1, params, inv_n);
    bn_apply<<<2048, 256, 0, stream>>>(h1, params, VC * 128);
    conv_mfma<2><<<nblk2, 512, 0, stream>>>(h1, cn, w2f, h2, stats + 128, VC);
    bn_params<<<1, 64, 0, stream>>>(stats + 128, g2, be2, params + 128, inv_n);
    final_out<<<(VC + 63) / 64, 256, 0, stream>>>(h2, params + 128, out, VC);
}